// Round 4
// baseline (61.736 us; speedup 1.0000x reference)
//
#include <hip/hip_runtime.h>
#include <math.h>

#define D_DIM 1024
#define TEMP_INV 14.285714285714286f   // 1/0.07
#define L2EPS 1e-12f
#define RPW 8                          // rows per wave

typedef float f32x4 __attribute__((ext_vector_type(4)));

// ws layout (floats): [0]nv [1]na [2]nt [3]dva [4]dvt [5]d0a [6]d0t, each N long

__device__ __forceinline__ float dot4(const f32x4 p, const f32x4 q) {
    return p.x*q.x + p.y*q.y + p.z*q.z + p.w*q.w;
}

// Forced-issue 16B load. Result NOT valid until an explicit s_waitcnt.
#define GLOAD4(dst, base, imm)                                          \
    asm volatile("global_load_dwordx4 %0, %1, off offset:" #imm         \
                 : "=v"(dst) : "v"(base))

#define ISSUE_ROW(b, vp, ap, tp)                                        \
    do {                                                                \
        GLOAD4(V[b][0], vp, 0);    GLOAD4(V[b][1], vp, 1024);           \
        GLOAD4(V[b][2], vp, 2048); GLOAD4(V[b][3], vp, 3072);           \
        GLOAD4(A[b][0], ap, 0);    GLOAD4(A[b][1], ap, 1024);           \
        GLOAD4(A[b][2], ap, 2048); GLOAD4(A[b][3], ap, 3072);           \
        GLOAD4(T[b][0], tp, 0);    GLOAD4(T[b][1], tp, 1024);           \
        GLOAD4(T[b][2], tp, 2048); GLOAD4(T[b][3], tp, 3072);           \
    } while (0)

__global__ __launch_bounds__(256) void nce_rowstats(
    const float* __restrict__ v, const float* __restrict__ a,
    const float* __restrict__ t, float* __restrict__ ws, int N)
{
    const int tid  = threadIdx.x;
    const int wave = tid >> 6;
    const int lane = tid & 63;
    const int wg   = blockIdx.x * 4 + wave;     // global wave id
    const int row0 = wg * RPW;
    if (row0 >= N) return;

    const float* vp = v + (size_t)row0 * D_DIM + lane * 4;
    const float* ap = a + (size_t)row0 * D_DIM + lane * 4;
    const float* tp = t + (size_t)row0 * D_DIM + lane * 4;
    const float* zp = v + lane * 4;             // row 0 of v

    f32x4 V[2][4], A[2][4], T[2][4];
    f32x4 Z0, Z1, Z2, Z3;

    // v0 loaded ONCE per wave, lives in registers for all 8 rows
    GLOAD4(Z0, zp, 0);    GLOAD4(Z1, zp, 1024);
    GLOAD4(Z2, zp, 2048); GLOAD4(Z3, zp, 3072);
    ISSUE_ROW(0, vp, ap, tp);                   // prologue: row 0 in flight

    #pragma unroll
    for (int i = 0; i < RPW; ++i) {
        const int b  = i & 1;
        const int nb = b ^ 1;
        if (i + 1 < RPW) {
            vp += D_DIM; ap += D_DIM; tp += D_DIM;
            ISSUE_ROW(nb, vp, ap, tp);          // next row: 12 loads in flight
            asm volatile("s_waitcnt vmcnt(12)" ::: "memory");
        } else {
            asm volatile("s_waitcnt vmcnt(0)" ::: "memory");
        }
        __builtin_amdgcn_sched_barrier(0);      // rule #18

        float sv  = dot4(V[b][0],V[b][0]) + dot4(V[b][1],V[b][1]) + dot4(V[b][2],V[b][2]) + dot4(V[b][3],V[b][3]);
        float sa  = dot4(A[b][0],A[b][0]) + dot4(A[b][1],A[b][1]) + dot4(A[b][2],A[b][2]) + dot4(A[b][3],A[b][3]);
        float st  = dot4(T[b][0],T[b][0]) + dot4(T[b][1],T[b][1]) + dot4(T[b][2],T[b][2]) + dot4(T[b][3],T[b][3]);
        float dva = dot4(V[b][0],A[b][0]) + dot4(V[b][1],A[b][1]) + dot4(V[b][2],A[b][2]) + dot4(V[b][3],A[b][3]);
        float dvt = dot4(V[b][0],T[b][0]) + dot4(V[b][1],T[b][1]) + dot4(V[b][2],T[b][2]) + dot4(V[b][3],T[b][3]);
        float d0a = dot4(Z0,A[b][0]) + dot4(Z1,A[b][1]) + dot4(Z2,A[b][2]) + dot4(Z3,A[b][3]);
        float d0t = dot4(Z0,T[b][0]) + dot4(Z1,T[b][1]) + dot4(Z2,T[b][2]) + dot4(Z3,T[b][3]);

        #pragma unroll
        for (int off = 32; off >= 1; off >>= 1) {
            sv  += __shfl_down(sv,  off);
            sa  += __shfl_down(sa,  off);
            st  += __shfl_down(st,  off);
            dva += __shfl_down(dva, off);
            dvt += __shfl_down(dvt, off);
            d0a += __shfl_down(d0a, off);
            d0t += __shfl_down(d0t, off);
        }

        if (lane == 0) {
            const int row = row0 + i;
            ws[0*N + row] = sqrtf(sv);
            ws[1*N + row] = sqrtf(sa);
            ws[2*N + row] = sqrtf(st);
            ws[3*N + row] = dva;
            ws[4*N + row] = dvt;
            ws[5*N + row] = d0a;
            ws[6*N + row] = d0t;
        }
    }
}

__device__ __forceinline__ float block_reduce_1024(float val, float* sred) {
    const int lane = threadIdx.x & 63;
    const int wave = threadIdx.x >> 6;
    __syncthreads();
    #pragma unroll
    for (int off = 32; off >= 1; off >>= 1) val += __shfl_down(val, off);
    if (lane == 0) sred[wave] = val;
    __syncthreads();
    float r = 0.f;
    if (wave == 0) {
        r = (lane < 16) ? sred[lane] : 0.f;
        #pragma unroll
        for (int off = 8; off >= 1; off >>= 1) r += __shfl_down(r, off);
        if (lane == 0) sred[0] = r;
    }
    __syncthreads();
    return sred[0];
}

__global__ __launch_bounds__(1024) void nce_finalize(
    const float* __restrict__ v, const float* __restrict__ a,
    const float* __restrict__ t, const float* __restrict__ ws,
    float* __restrict__ out, int N)
{
    __shared__ float sred[16];
    const int tid = threadIdx.x;

    const float* nv  = ws + 0 * (size_t)N;
    const float* na  = ws + 1 * (size_t)N;
    const float* nt  = ws + 2 * (size_t)N;
    const float* dva = ws + 3 * (size_t)N;
    const float* dvt = ws + 4 * (size_t)N;
    const float* d0a = ws + 5 * (size_t)N;
    const float* d0t = ws + 6 * (size_t)N;

    const float nv0 = fmaxf(nv[0], L2EPS);
    const float nv1 = fmaxf(nv[1], L2EPS);
    const float na0 = fmaxf(na[0], L2EPS);
    const float nt0 = fmaxf(nt[0], L2EPS);

    float pea = v[D_DIM + tid] * a[tid];
    float pet = v[D_DIM + tid] * t[tid];
    const float ea = block_reduce_1024(pea, sred);
    const float et = block_reduce_1024(pet, sred);

    float sna = 0.f, snt = 0.f;
    for (int j = tid; j < N; j += 1024) {
        if (j == 0) continue;
        const float inv_a = 1.0f / (nv0 * fmaxf(na[j], L2EPS));
        const float inv_t = 1.0f / (nv0 * fmaxf(nt[j], L2EPS));
        sna += expf(d0a[j] * inv_a * TEMP_INV);
        snt += expf(d0t[j] * inv_t * TEMP_INV);
    }
    float sum_neg_a = block_reduce_1024(sna, sred);
    float sum_neg_t = block_reduce_1024(snt, sred);
    sum_neg_a += expf(ea / (nv1 * na0) * TEMP_INV);
    sum_neg_t += expf(et / (nv1 * nt0) * TEMP_INV);

    float la = 0.f, lt = 0.f;
    for (int k = tid; k < N; k += 1024) {
        const float nvk = fmaxf(nv[k], L2EPS);
        const float pos_a = dva[k] / (nvk * fmaxf(na[k], L2EPS)) * TEMP_INV;
        const float pos_t = dvt[k] / (nvk * fmaxf(nt[k], L2EPS)) * TEMP_INV;
        float lla = logf(expf(pos_a) + sum_neg_a) - pos_a;
        float llt = logf(expf(pos_t) + sum_neg_t) - pos_t;
        if (isnan(lla)) lla = 0.f;
        if (isnan(llt)) llt = 0.f;
        la += lla;
        lt += llt;
    }
    la = block_reduce_1024(la, sred);
    lt = block_reduce_1024(lt, sred);

    if (tid == 0) {
        out[0] = la / (float)N;
        out[1] = lt / (float)N;
    }
}

extern "C" void kernel_launch(void* const* d_in, const int* in_sizes, int n_in,
                              void* d_out, int out_size, void* d_ws, size_t ws_size,
                              hipStream_t stream) {
    const float* v = (const float*)d_in[0];
    const float* a = (const float*)d_in[1];
    const float* t = (const float*)d_in[2];
    float* out = (float*)d_out;
    float* ws  = (float*)d_ws;
    const int N = in_sizes[0] / D_DIM;   // 16384

    const int blocks = (N + 4 * RPW - 1) / (4 * RPW);   // 512: one wave per 8 rows
    nce_rowstats<<<blocks, 256, 0, stream>>>(v, a, t, ws, N);
    nce_finalize<<<1, 1024, 0, stream>>>(v, a, t, ws, out, N);
}

// Round 5
// 60.221 us; speedup vs baseline: 1.0252x; 1.0252x over previous
//
#include <hip/hip_runtime.h>
#include <math.h>

#define D_DIM 1024
#define TEMP_INV 14.285714285714286f   // 1/0.07
#define L2EPS 1e-12f

typedef float f32x4 __attribute__((ext_vector_type(4)));

// ws layout (floats): [0]nv [1]na [2]nt [3]dva [4]dvt [5]d0a [6]d0t, each N long

__device__ __forceinline__ float dot4(const f32x4 p, const f32x4 q) {
    return p.x*q.x + p.y*q.y + p.z*q.z + p.w*q.w;
}

__global__ __launch_bounds__(256) void nce_rowstats(
    const float* __restrict__ v, const float* __restrict__ a,
    const float* __restrict__ t, float* __restrict__ ws, int N)
{
    __shared__ f32x4 v0s[256];           // row 0 of v (4 KB), cached loads
    const int tid  = threadIdx.x;
    const int wave = tid >> 6;
    const int lane = tid & 63;
    const int row  = blockIdx.x * 4 + wave;

    v0s[tid] = ((const f32x4*)v)[tid];   // normal (cached) load — v0 is hot
    __syncthreads();

    if (row >= N) return;

    const f32x4* vr = (const f32x4*)(v + (size_t)row * D_DIM);
    const f32x4* ar = (const f32x4*)(a + (size_t)row * D_DIM);
    const f32x4* tr = (const f32x4*)(t + (size_t)row * D_DIM);

    // ---- streaming loads: NON-TEMPORAL (bypass L3; pure HBM) ----
    const f32x4 V0 = __builtin_nontemporal_load(vr + lane      );
    const f32x4 V1 = __builtin_nontemporal_load(vr + lane +  64);
    const f32x4 V2 = __builtin_nontemporal_load(vr + lane + 128);
    const f32x4 V3 = __builtin_nontemporal_load(vr + lane + 192);
    const f32x4 A0 = __builtin_nontemporal_load(ar + lane      );
    const f32x4 A1 = __builtin_nontemporal_load(ar + lane +  64);
    const f32x4 A2 = __builtin_nontemporal_load(ar + lane + 128);
    const f32x4 A3 = __builtin_nontemporal_load(ar + lane + 192);
    const f32x4 T0 = __builtin_nontemporal_load(tr + lane      );
    const f32x4 T1 = __builtin_nontemporal_load(tr + lane +  64);
    const f32x4 T2 = __builtin_nontemporal_load(tr + lane + 128);
    const f32x4 T3 = __builtin_nontemporal_load(tr + lane + 192);

    const f32x4 Z0 = v0s[lane      ];
    const f32x4 Z1 = v0s[lane +  64];
    const f32x4 Z2 = v0s[lane + 128];
    const f32x4 Z3 = v0s[lane + 192];

    float sv  = dot4(V0,V0) + dot4(V1,V1) + dot4(V2,V2) + dot4(V3,V3);
    float sa  = dot4(A0,A0) + dot4(A1,A1) + dot4(A2,A2) + dot4(A3,A3);
    float st  = dot4(T0,T0) + dot4(T1,T1) + dot4(T2,T2) + dot4(T3,T3);
    float dva = dot4(V0,A0) + dot4(V1,A1) + dot4(V2,A2) + dot4(V3,A3);
    float dvt = dot4(V0,T0) + dot4(V1,T1) + dot4(V2,T2) + dot4(V3,T3);
    float d0a = dot4(Z0,A0) + dot4(Z1,A1) + dot4(Z2,A2) + dot4(Z3,A3);
    float d0t = dot4(Z0,T0) + dot4(Z1,T1) + dot4(Z2,T2) + dot4(Z3,T3);

    // wave (64-lane) butterfly reduce of 7 values
    #pragma unroll
    for (int off = 32; off >= 1; off >>= 1) {
        sv  += __shfl_down(sv,  off);
        sa  += __shfl_down(sa,  off);
        st  += __shfl_down(st,  off);
        dva += __shfl_down(dva, off);
        dvt += __shfl_down(dvt, off);
        d0a += __shfl_down(d0a, off);
        d0t += __shfl_down(d0t, off);
    }

    if (lane == 0) {
        ws[0*N + row] = sqrtf(sv);
        ws[1*N + row] = sqrtf(sa);
        ws[2*N + row] = sqrtf(st);
        ws[3*N + row] = dva;
        ws[4*N + row] = dvt;
        ws[5*N + row] = d0a;
        ws[6*N + row] = d0t;
    }
}

__device__ __forceinline__ float block_reduce_1024(float val, float* sred) {
    const int lane = threadIdx.x & 63;
    const int wave = threadIdx.x >> 6;
    __syncthreads();
    #pragma unroll
    for (int off = 32; off >= 1; off >>= 1) val += __shfl_down(val, off);
    if (lane == 0) sred[wave] = val;
    __syncthreads();
    float r = 0.f;
    if (wave == 0) {
        r = (lane < 16) ? sred[lane] : 0.f;
        #pragma unroll
        for (int off = 8; off >= 1; off >>= 1) r += __shfl_down(r, off);
        if (lane == 0) sred[0] = r;
    }
    __syncthreads();
    return sred[0];
}

__global__ __launch_bounds__(1024) void nce_finalize(
    const float* __restrict__ v, const float* __restrict__ a,
    const float* __restrict__ t, const float* __restrict__ ws,
    float* __restrict__ out, int N)
{
    __shared__ float sred[16];
    const int tid = threadIdx.x;

    const float* nv  = ws + 0 * (size_t)N;
    const float* na  = ws + 1 * (size_t)N;
    const float* nt  = ws + 2 * (size_t)N;
    const float* dva = ws + 3 * (size_t)N;
    const float* dvt = ws + 4 * (size_t)N;
    const float* d0a = ws + 5 * (size_t)N;
    const float* d0t = ws + 6 * (size_t)N;

    const float nv0 = fmaxf(nv[0], L2EPS);
    const float nv1 = fmaxf(nv[1], L2EPS);
    const float na0 = fmaxf(na[0], L2EPS);
    const float nt0 = fmaxf(nt[0], L2EPS);

    float pea = v[D_DIM + tid] * a[tid];
    float pet = v[D_DIM + tid] * t[tid];
    const float ea = block_reduce_1024(pea, sred);
    const float et = block_reduce_1024(pet, sred);

    float sna = 0.f, snt = 0.f;
    for (int j = tid; j < N; j += 1024) {
        if (j == 0) continue;
        const float inv_a = 1.0f / (nv0 * fmaxf(na[j], L2EPS));
        const float inv_t = 1.0f / (nv0 * fmaxf(nt[j], L2EPS));
        sna += expf(d0a[j] * inv_a * TEMP_INV);
        snt += expf(d0t[j] * inv_t * TEMP_INV);
    }
    float sum_neg_a = block_reduce_1024(sna, sred);
    float sum_neg_t = block_reduce_1024(snt, sred);
    sum_neg_a += expf(ea / (nv1 * na0) * TEMP_INV);
    sum_neg_t += expf(et / (nv1 * nt0) * TEMP_INV);

    float la = 0.f, lt = 0.f;
    for (int k = tid; k < N; k += 1024) {
        const float nvk = fmaxf(nv[k], L2EPS);
        const float pos_a = dva[k] / (nvk * fmaxf(na[k], L2EPS)) * TEMP_INV;
        const float pos_t = dvt[k] / (nvk * fmaxf(nt[k], L2EPS)) * TEMP_INV;
        float lla = logf(expf(pos_a) + sum_neg_a) - pos_a;
        float llt = logf(expf(pos_t) + sum_neg_t) - pos_t;
        if (isnan(lla)) lla = 0.f;
        if (isnan(llt)) llt = 0.f;
        la += lla;
        lt += llt;
    }
    la = block_reduce_1024(la, sred);
    lt = block_reduce_1024(lt, sred);

    if (tid == 0) {
        out[0] = la / (float)N;
        out[1] = lt / (float)N;
    }
}

extern "C" void kernel_launch(void* const* d_in, const int* in_sizes, int n_in,
                              void* d_out, int out_size, void* d_ws, size_t ws_size,
                              hipStream_t stream) {
    const float* v = (const float*)d_in[0];
    const float* a = (const float*)d_in[1];
    const float* t = (const float*)d_in[2];
    float* out = (float*)d_out;
    float* ws  = (float*)d_ws;
    const int N = in_sizes[0] / D_DIM;   // 16384

    const int blocks = (N + 3) / 4;      // one 64-lane wave per row
    nce_rowstats<<<blocks, 256, 0, stream>>>(v, a, t, ws, N);
    nce_finalize<<<1, 1024, 0, stream>>>(v, a, t, ws, out, N);
}

// Round 6
// 42.177 us; speedup vs baseline: 1.4637x; 1.4278x over previous
//
#include <hip/hip_runtime.h>
#include <math.h>

#define D_DIM 1024
#define TEMP_INV 14.285714285714286f   // 1/0.07
#define L2EPS 1e-12f

typedef float f32x4 __attribute__((ext_vector_type(4)));

// ws layout (floats):
//  [0*N..1*N) nv   [1*N..2*N) na   [2*N..3*N) nt
//  [3*N..4*N) dva  [4*N..5*N) dvt  [5*N..6*N) d0a  [6*N..7*N) d0t
//  B = 7*N scalar/partial area:
//  B+0..31   sna partials     B+32..63  snt partials
//  B+64 ea_raw  B+65 et_raw
//  B+96..127 loss_a partials  B+128..159 loss_t partials

__device__ __forceinline__ float dot4(const f32x4 p, const f32x4 q) {
    return p.x*q.x + p.y*q.y + p.z*q.z + p.w*q.w;
}

__global__ __launch_bounds__(256) void nce_rowstats(
    const float* __restrict__ v, const float* __restrict__ a,
    const float* __restrict__ t, float* __restrict__ ws, int N)
{
    __shared__ f32x4 v0s[256];           // row 0 of v (4 KB), cached loads
    const int tid  = threadIdx.x;
    const int wave = tid >> 6;
    const int lane = tid & 63;
    const int row  = blockIdx.x * 4 + wave;

    v0s[tid] = ((const f32x4*)v)[tid];   // normal (cached) load — v0 is hot
    __syncthreads();

    if (row >= N) return;

    const f32x4* vr = (const f32x4*)(v + (size_t)row * D_DIM);
    const f32x4* ar = (const f32x4*)(a + (size_t)row * D_DIM);
    const f32x4* tr = (const f32x4*)(t + (size_t)row * D_DIM);

    // ---- streaming loads: NON-TEMPORAL (bypass L3; pure HBM) ----
    const f32x4 V0 = __builtin_nontemporal_load(vr + lane      );
    const f32x4 V1 = __builtin_nontemporal_load(vr + lane +  64);
    const f32x4 V2 = __builtin_nontemporal_load(vr + lane + 128);
    const f32x4 V3 = __builtin_nontemporal_load(vr + lane + 192);
    const f32x4 A0 = __builtin_nontemporal_load(ar + lane      );
    const f32x4 A1 = __builtin_nontemporal_load(ar + lane +  64);
    const f32x4 A2 = __builtin_nontemporal_load(ar + lane + 128);
    const f32x4 A3 = __builtin_nontemporal_load(ar + lane + 192);
    const f32x4 T0 = __builtin_nontemporal_load(tr + lane      );
    const f32x4 T1 = __builtin_nontemporal_load(tr + lane +  64);
    const f32x4 T2 = __builtin_nontemporal_load(tr + lane + 128);
    const f32x4 T3 = __builtin_nontemporal_load(tr + lane + 192);

    const f32x4 Z0 = v0s[lane      ];
    const f32x4 Z1 = v0s[lane +  64];
    const f32x4 Z2 = v0s[lane + 128];
    const f32x4 Z3 = v0s[lane + 192];

    float sv  = dot4(V0,V0) + dot4(V1,V1) + dot4(V2,V2) + dot4(V3,V3);
    float sa  = dot4(A0,A0) + dot4(A1,A1) + dot4(A2,A2) + dot4(A3,A3);
    float st  = dot4(T0,T0) + dot4(T1,T1) + dot4(T2,T2) + dot4(T3,T3);
    float dva = dot4(V0,A0) + dot4(V1,A1) + dot4(V2,A2) + dot4(V3,A3);
    float dvt = dot4(V0,T0) + dot4(V1,T1) + dot4(V2,T2) + dot4(V3,T3);
    float d0a = dot4(Z0,A0) + dot4(Z1,A1) + dot4(Z2,A2) + dot4(Z3,A3);
    float d0t = dot4(Z0,T0) + dot4(Z1,T1) + dot4(Z2,T2) + dot4(Z3,T3);

    #pragma unroll
    for (int off = 32; off >= 1; off >>= 1) {
        sv  += __shfl_down(sv,  off);
        sa  += __shfl_down(sa,  off);
        st  += __shfl_down(st,  off);
        dva += __shfl_down(dva, off);
        dvt += __shfl_down(dvt, off);
        d0a += __shfl_down(d0a, off);
        d0t += __shfl_down(d0t, off);
    }

    if (lane == 0) {
        ws[0*N + row] = sqrtf(sv);
        ws[1*N + row] = sqrtf(sa);
        ws[2*N + row] = sqrtf(st);
        ws[3*N + row] = dva;
        ws[4*N + row] = dvt;
        ws[5*N + row] = d0a;
        ws[6*N + row] = d0t;
    }
}

// reduce two values across 256 threads; valid in thread 0 only
__device__ __forceinline__ void block_reduce2_256(float& x, float& y, float* sred) {
    const int lane = threadIdx.x & 63;
    const int wave = threadIdx.x >> 6;
    #pragma unroll
    for (int off = 32; off >= 1; off >>= 1) {
        x += __shfl_down(x, off);
        y += __shfl_down(y, off);
    }
    if (lane == 0) { sred[wave] = x; sred[4 + wave] = y; }
    __syncthreads();
    if (threadIdx.x == 0) {
        x = sred[0] + sred[1] + sred[2] + sred[3];
        y = sred[4] + sred[5] + sred[6] + sred[7];
    }
}

__global__ __launch_bounds__(256) void nce_partials(
    const float* __restrict__ v, const float* __restrict__ a,
    const float* __restrict__ t, float* __restrict__ ws, int N)
{
    __shared__ float sred[8];
    const int tid = threadIdx.x;
    const int bid = blockIdx.x;
    const size_t B = 7 * (size_t)N;

    float r1 = 0.f, r2 = 0.f;
    if (bid < 32) {
        const float nv0 = fmaxf(ws[0], L2EPS);      // nv[0]
        #pragma unroll
        for (int k = 0; k < 2; ++k) {
            const int j = bid * 512 + k * 256 + tid;
            if (j == 0) continue;
            const float ia = 1.0f / (nv0 * fmaxf(ws[1*N + j], L2EPS));
            const float it = 1.0f / (nv0 * fmaxf(ws[2*N + j], L2EPS));
            r1 += expf(ws[5*N + j] * ia * TEMP_INV);
            r2 += expf(ws[6*N + j] * it * TEMP_INV);
        }
    } else {
        // raw dots v1.a0, v1.t0 (one float4 per thread covers D=1024)
        const f32x4 vv = *(const f32x4*)(v + D_DIM + 4 * tid);
        const f32x4 aa = *(const f32x4*)(a + 4 * tid);
        const f32x4 tt = *(const f32x4*)(t + 4 * tid);
        r1 = dot4(vv, aa);
        r2 = dot4(vv, tt);
    }
    block_reduce2_256(r1, r2, sred);
    if (tid == 0) {
        if (bid < 32) { ws[B + bid] = r1; ws[B + 32 + bid] = r2; }
        else          { ws[B + 64]  = r1; ws[B + 65]  = r2; }
    }
}

__global__ __launch_bounds__(256) void nce_loss(
    float* __restrict__ ws, int N)
{
    __shared__ float sred[8];
    const int tid = threadIdx.x;
    const int bid = blockIdx.x;
    const size_t B = 7 * (size_t)N;

    // every block deterministically combines the 33 partials
    float sna = 0.f, snt = 0.f;
    #pragma unroll
    for (int i = 0; i < 32; ++i) { sna += ws[B + i]; snt += ws[B + 32 + i]; }
    const float nv1 = fmaxf(ws[0*N + 1], L2EPS);
    const float na0 = fmaxf(ws[1*N + 0], L2EPS);
    const float nt0 = fmaxf(ws[2*N + 0], L2EPS);
    const float sum_neg_a = sna + expf(ws[B + 64] / (nv1 * na0) * TEMP_INV);
    const float sum_neg_t = snt + expf(ws[B + 65] / (nv1 * nt0) * TEMP_INV);

    float la = 0.f, lt = 0.f;
    #pragma unroll
    for (int k = 0; k < 2; ++k) {
        const int kk = bid * 512 + k * 256 + tid;
        const float nvk = fmaxf(ws[0*N + kk], L2EPS);
        const float pos_a = ws[3*N + kk] / (nvk * fmaxf(ws[1*N + kk], L2EPS)) * TEMP_INV;
        const float pos_t = ws[4*N + kk] / (nvk * fmaxf(ws[2*N + kk], L2EPS)) * TEMP_INV;
        float lla = logf(expf(pos_a) + sum_neg_a) - pos_a;
        float llt = logf(expf(pos_t) + sum_neg_t) - pos_t;
        if (isnan(lla)) lla = 0.f;
        if (isnan(llt)) llt = 0.f;
        la += lla;
        lt += llt;
    }
    block_reduce2_256(la, lt, sred);
    if (tid == 0) { ws[B + 96 + bid] = la; ws[B + 128 + bid] = lt; }
}

__global__ __launch_bounds__(64) void nce_out(
    const float* __restrict__ ws, float* __restrict__ out, int N)
{
    const int lane = threadIdx.x;
    const size_t B = 7 * (size_t)N;
    float xa = (lane < 32) ? ws[B + 96 + lane]  : 0.f;
    float xt = (lane < 32) ? ws[B + 128 + lane] : 0.f;
    #pragma unroll
    for (int off = 32; off >= 1; off >>= 1) {
        xa += __shfl_down(xa, off);
        xt += __shfl_down(xt, off);
    }
    if (lane == 0) {
        out[0] = xa / (float)N;
        out[1] = xt / (float)N;
    }
}

extern "C" void kernel_launch(void* const* d_in, const int* in_sizes, int n_in,
                              void* d_out, int out_size, void* d_ws, size_t ws_size,
                              hipStream_t stream) {
    const float* v = (const float*)d_in[0];
    const float* a = (const float*)d_in[1];
    const float* t = (const float*)d_in[2];
    float* out = (float*)d_out;
    float* ws  = (float*)d_ws;
    const int N = in_sizes[0] / D_DIM;   // 16384

    const int blocks = (N + 3) / 4;      // one 64-lane wave per row
    nce_rowstats<<<blocks, 256, 0, stream>>>(v, a, t, ws, N);
    nce_partials<<<33, 256, 0, stream>>>(v, a, t, ws, N);
    nce_loss<<<32, 256, 0, stream>>>(ws, N);
    nce_out<<<1, 64, 0, stream>>>(ws, out, N);
}